// Round 1
// baseline (449.620 us; speedup 1.0000x reference)
//
#include <hip/hip_runtime.h>
#include <math.h>

#define WIN 11
#define PAD 5
#define TW 64              // tile width = wave width

typedef float v2f __attribute__((ext_vector_type(2)));

struct GW { float g[WIN]; };

// ---------------------------------------------------------------------------
// Wave-autonomous SSIM tile. One wave streams a TWxTH output tile, no block
// barriers. Per row t: prefetched global load -> wave-private LDS row
// (float2 (p,q)=(a+b,a-b), wave_barrier-ordered) -> 11 ds_read_b64/lane ->
// PACKED H-conv (v_pk_fma_f32 on (p,q): hM=(hp,hq), hS=(hpp,hqq)) ->
// PACKED shift-register V-conv: slot k holds output o=t-10+k; each step adds
// g[10-k]*h; emits slot 0 when t>=10, shifts (v_mov_b64), zeroes slot 10.
// Packed fp32 halves the conv VALU count vs scalar (66->33 H, 44->22 V);
// numerics are bit-identical (same op order/rounding as the scalar version).
// TH=32 (L0) / TH=16 (rest) doubles/quadruples wave parallelism vs TH=64:
// the kernel is latency-bound (VALUBusy 53%, occ 25%, HBM 11%), so waves
// buy more than the +13% halo-row overhead costs.
// EMIT: L0 waves also pool rows pairwise into L1 (a=(P+Q)/2, b=(P-Q)/2).
// ---------------------------------------------------------------------------
template<bool EMIT, int TH>
__device__ __forceinline__ float ssim_wave_tile(
    const float* __restrict__ p1, const float* __restrict__ p2,
    int W, int X0, int Y0, const GW& gw, v2f* __restrict__ rb,
    float* __restrict__ o1a, float* __restrict__ o1b, int Wout)
{
    const int lane = threadIdx.x & 63;
    const int gx = X0 + lane;
    const bool cval = gx < W;                              // false only for L4 lanes 32+
    const int hx   = (lane < 5) ? (X0 - 5 + lane) : (X0 + 59 + lane);
    const bool hval = (lane < 10) && ((unsigned)hx < (unsigned)W);
    const int hpos = (lane < 5) ? lane : (64 + lane);      // 0..4 | 69..73
    const int cpos = 5 + lane;

    v2f vM[11], vS[11];                                    // (Mp,Mq) / (Spp,Sqq)
#pragma unroll
    for (int k = 0; k < 11; ++k) { vM[k] = (v2f){0.f, 0.f}; vS[k] = (v2f){0.f, 0.f}; }

    float part = 0.f;
    v2f pqprev = {0.f, 0.f};
    float a, b, ah, bh;

    auto LOAD = [&](int t, float& oa, float& ob, float& oah, float& obh) {
        int y = Y0 - PAD + t;
        oa = 0.f; ob = 0.f; oah = 0.f; obh = 0.f;
        if ((unsigned)y < (unsigned)W) {
            const float* r1 = p1 + (size_t)y * W;
            const float* r2 = p2 + (size_t)y * W;
            if (cval) { oa  = r1[gx]; ob  = r2[gx]; }
            if (hval) { oah = r1[hx]; obh = r2[hx]; }
        }
    };

    LOAD(0, a, b, ah, bh);

#pragma unroll 2
    for (int t = 0; t < TH + 10; ++t) {
        // prefetch next row while computing this one
        float na, nb, nah, nbh;
        LOAD(t + 1, na, nb, nah, nbh);

        v2f pq = { a + b, a - b };
        v2f pqh = { ah + bh, ah - bh };
        rb[cpos] = pq;
        if (lane < 10) rb[hpos] = pqh;
        __builtin_amdgcn_wave_barrier();   // writes -> reads (cross-lane RAW)

        v2f hM = {0.f, 0.f}, hS = {0.f, 0.f};
#pragma unroll
        for (int j = 0; j < WIN; ++j) {
            v2f v = rb[lane + j];
            v2f g = { gw.g[j], gw.g[j] };
            hM = __builtin_elementwise_fma(g, v, hM);
            hS = __builtin_elementwise_fma(g, v * v, hS);
        }
        __builtin_amdgcn_wave_barrier();   // reads -> next row's writes (WAR)

        // V-conv shift-register accumulate: slot k <- g[10-k]*h (== g[t-o])
#pragma unroll
        for (int k = 0; k < 11; ++k) {
            v2f g = { gw.g[10 - k], gw.g[10 - k] };
            vM[k] = __builtin_elementwise_fma(g, hM, vM[k]);
            vS[k] = __builtin_elementwise_fma(g, hS, vS[k]);
        }

        if (EMIT) {
            if (t >= 6 && t <= TH + 4 && (t & 1) == 0) {   // pool rows (t-1, t)
                v2f s = pq + pqprev;
                float sp2 = s.x + __shfl_down(s.x, 1, 64);
                float sq2 = s.y + __shfl_down(s.y, 1, 64);
                if ((lane & 1) == 0) {
                    float P = sp2 * 0.25f, Q = sq2 * 0.25f;
                    int yo = (t - 6) >> 1;
                    size_t oo = (size_t)((Y0 >> 1) + yo) * Wout + ((X0 >> 1) + (lane >> 1));
                    o1a[oo] = (P + Q) * 0.5f;
                    o1b[oo] = (P - Q) * 0.5f;
                }
            }
            pqprev = pq;
        }

        if (t >= 10) {                               // output row o = t-10 from slot 0
            int o = t - 10;
            bool yok = (unsigned)(Y0 + o) < (unsigned)W;   // false only for L4 tail
            float Mp = vM[0].x, Mq = vM[0].y, Sp_ = vS[0].x, Sq_ = vS[0].y;
            const float C1v = 1e-4f, C2v = 9e-4f;
            float A = Mp * Mp, B = Mq * Mq;
            float ABp = A + B, ABm = A - B;
            float SSp = Sp_ + Sq_, SSm = Sp_ - Sq_;
            float n1 = fmaf(0.5f, ABm, C1v);         // 2*m12 + C1
            float n2 = fmaf(0.5f, SSm - ABm, C2v);   // 2*s12 + C2
            float e1 = fmaf(0.5f, ABp, C1v);         // m1^2+m2^2 + C1
            float e2 = fmaf(0.5f, SSp - ABp, C2v);   // s1+s2 + C2
            float v = (n1 * n2) * __builtin_amdgcn_rcpf(e1 * e2);
            part += (cval && yok) ? v : 0.f;
        }

        // shift down, clear slot 10 (v2f copies -> v_mov_b64)
#pragma unroll
        for (int k = 0; k < 10; ++k) { vM[k] = vM[k + 1]; vS[k] = vS[k + 1]; }
        vM[10] = (v2f){0.f, 0.f}; vS[10] = (v2f){0.f, 0.f};

        a = na; b = nb; ah = nah; bh = nbh;
    }

    return part;
}

// ---- L0: 8x16 tiles (64x32) x 48 images = 6144 waves (1536 blocks = 6/CU
//      exactly, single generation); emits L1 ----
__global__ __launch_bounds__(256, 6) void ssim_l0_kernel(
    const float* __restrict__ i1, const float* __restrict__ i2,
    float* __restrict__ a1, float* __restrict__ b1,
    double* __restrict__ acc, GW gw)
{
    __shared__ v2f rbs[4][80];
    const int wid = threadIdx.x >> 6;
    const int w = blockIdx.x * 4 + wid;
    const int img = w >> 7;                 // 128 tiles per image
    const int tt = w & 127;
    const int tx = tt & 7, ty = tt >> 3;    // 8 cols x 16 rows
    const size_t off  = (size_t)img * 512 * 512;
    const size_t ooff = (size_t)img * 256 * 256;

    float part = ssim_wave_tile<true, 32>(i1 + off, i2 + off, 512, tx * 64, ty * 32,
                                          gw, rbs[wid], a1 + ooff, b1 + ooff, 256);
#pragma unroll
    for (int o = 32; o > 0; o >>= 1) part += __shfl_down(part, o, 64);
    if ((threadIdx.x & 63) == 0) atomicAdd(acc, (double)part);
}

// ---- L1..L4 with 64x16 tiles: 64+16+4+2 = 86 tiles/image = 4128 waves
//      (1032 blocks -- fully resident at 6 blocks/CU, no straggler tail) ----
__global__ __launch_bounds__(256, 6) void ssim_rest_kernel(
    const float* __restrict__ a1, const float* __restrict__ b1,
    const float* __restrict__ a2, const float* __restrict__ b2,
    const float* __restrict__ a3, const float* __restrict__ b3,
    const float* __restrict__ a4, const float* __restrict__ b4,
    double* __restrict__ acc, GW gw)
{
    __shared__ v2f rbs[4][80];
    const int wid = threadIdx.x >> 6;
    const int w = blockIdx.x * 4 + wid;
    const int img = w / 86;
    const int r = w - img * 86;
    int lvl, tx, ty;
    if (r < 64)      { lvl = 1; tx = r & 3;  ty = r >> 2; }          // 4x16
    else if (r < 80) { lvl = 2; int s = r - 64; tx = s & 1; ty = s >> 1; } // 2x8
    else if (r < 84) { lvl = 3; tx = 0; ty = r - 80; }               // 1x4
    else             { lvl = 4; tx = 0; ty = r - 84; }               // 1x2
    const int W = 512 >> lvl;
    const float* p1; const float* p2;
    switch (lvl) {
      case 1:  p1 = a1; p2 = b1; break;
      case 2:  p1 = a2; p2 = b2; break;
      case 3:  p1 = a3; p2 = b3; break;
      default: p1 = a4; p2 = b4; break;
    }
    const size_t off = (size_t)img * W * W;

    float part = ssim_wave_tile<false, 16>(p1 + off, p2 + off, W, tx * 64, ty * 16,
                                           gw, rbs[wid], nullptr, nullptr, 0);
#pragma unroll
    for (int o = 32; o > 0; o >>= 1) part += __shfl_down(part, o, 64);
    if ((threadIdx.x & 63) == 0) atomicAdd(acc + lvl, (double)part);
}

// ---- pool L1 -> L2/L3/L4. Grid (16, 96). ----
__global__ __launch_bounds__(256) void pool_rest_kernel(
    const float* __restrict__ a1, const float* __restrict__ b1,
    float* __restrict__ a2, float* __restrict__ b2,
    float* __restrict__ a3, float* __restrict__ b3,
    float* __restrict__ a4, float* __restrict__ b4)
{
    __shared__ float l2[32][33];
    __shared__ float l3[16][17];
    const int tid = threadIdx.x;
    const int im = blockIdx.y;
    const int tb = blockIdx.x;
    const int tx = tb & 3, ty = tb >> 2;
    const bool second = im >= 48;
    const int ii = second ? im - 48 : im;
    const float* src = (second ? b1 : a1) + (size_t)ii * 256 * 256;
    float* o2 = (second ? b2 : a2) + (size_t)ii * 128 * 128;
    float* o3 = (second ? b3 : a3) + (size_t)ii * 64 * 64;
    float* o4 = (second ? b4 : a4) + (size_t)ii * 32 * 32;
    const int X0 = tx * 64, Y0 = ty * 64;

#pragma unroll
    for (int k = 0; k < 2; ++k) {
        int idx = tid + k * 256;
        int xp = idx & 15;
        int yo = idx >> 4;
        const float* rp = src + (size_t)(Y0 + 2 * yo) * 256 + (X0 + 4 * xp);
        float4 r0 = *(const float4*)rp;
        float4 r1 = *(const float4*)(rp + 256);
        float v0 = (r0.x + r0.y + r1.x + r1.y) * 0.25f;
        float v1 = (r0.z + r0.w + r1.z + r1.w) * 0.25f;
        l2[yo][2 * xp]     = v0;
        l2[yo][2 * xp + 1] = v1;
        float2* op = (float2*)(o2 + (size_t)((Y0 >> 1) + yo) * 128 + ((X0 >> 1) + 2 * xp));
        *op = make_float2(v0, v1);
    }
    __syncthreads();
    {
        int xo = tid & 15, yo = tid >> 4;
        if (yo < 16) {
            float v = (l2[2*yo][2*xo] + l2[2*yo][2*xo+1] +
                       l2[2*yo+1][2*xo] + l2[2*yo+1][2*xo+1]) * 0.25f;
            l3[yo][xo] = v;
            o3[(size_t)((Y0 >> 2) + yo) * 64 + ((X0 >> 2) + xo)] = v;
        }
    }
    __syncthreads();
    if (tid < 64) {
        int xo = tid & 7, yo = tid >> 3;
        float v = (l3[2*yo][2*xo] + l3[2*yo][2*xo+1] +
                   l3[2*yo+1][2*xo] + l3[2*yo+1][2*xo+1]) * 0.25f;
        o4[(size_t)((Y0 >> 3) + yo) * 32 + ((X0 >> 3) + xo)] = v;
    }
}

__global__ void final_kernel(const double* __restrict__ acc, float* __restrict__ out)
{
    double loss = 0.0;
#pragma unroll
    for (int l = 0; l < 5; ++l) {
        double cnt = 48.0 * (double)(512 >> l) * (double)(512 >> l);
        loss += 1.0 - acc[l] / cnt;
    }
    out[0] = (float)loss;
}

extern "C" void kernel_launch(void* const* d_in, const int* in_sizes, int n_in,
                              void* d_out, int out_size, void* d_ws, size_t ws_size,
                              hipStream_t stream)
{
    const float* img1 = (const float*)d_in[0];
    const float* img2 = (const float*)d_in[1];
    float* out = (float*)d_out;

    // 1D gaussian (sigma=1.5, k=11), matches reference construction
    GW gw;
    double gs[WIN], sum = 0.0;
    for (int i = 0; i < WIN; ++i) {
        double ax = (double)i - 5.0;
        gs[i] = exp(-(ax * ax) / 4.5);
        sum += gs[i];
    }
    for (int i = 0; i < WIN; ++i) gw.g[i] = (float)(gs[i] / sum);

    // workspace: 64B header (5 double acc), then pyramid
    double* acc = (double*)d_ws;
    float* base = (float*)((char*)d_ws + 64);
    const size_t n1 = 48ull * 256 * 256;
    const size_t n2 = 48ull * 128 * 128;
    const size_t n3 = 48ull * 64 * 64;
    const size_t n4 = 48ull * 32 * 32;
    float* a1 = base;      float* b1 = a1 + n1;
    float* a2 = b1 + n1;   float* b2 = a2 + n2;
    float* a3 = b2 + n2;   float* b3 = a3 + n3;
    float* a4 = b3 + n3;   float* b4 = a4 + n4;

    hipMemsetAsync(acc, 0, 5 * sizeof(double), stream);

    hipLaunchKernelGGL(ssim_l0_kernel, dim3(1536), dim3(256), 0, stream,
                       img1, img2, a1, b1, acc, gw);

    hipLaunchKernelGGL(pool_rest_kernel, dim3(16, 96), dim3(256), 0, stream,
                       a1, b1, a2, b2, a3, b3, a4, b4);

    hipLaunchKernelGGL(ssim_rest_kernel, dim3(1032), dim3(256), 0, stream,
                       a1, b1, a2, b2, a3, b3, a4, b4, acc, gw);

    hipLaunchKernelGGL(final_kernel, dim3(1), dim3(1), 0, stream, acc, out);
}

// Round 2
// 304.086 us; speedup vs baseline: 1.4786x; 1.4786x over previous
//
#include <hip/hip_runtime.h>
#include <math.h>

#define WIN 11
#define PAD 5
#define TW 64              // tile width = wave width

struct GW { float g[WIN]; };

// ---------------------------------------------------------------------------
// Wave-autonomous SSIM tile (R0 scalar body — verified spill-free at 56 VGPR —
// with the TH-templated tiling from R1 for occupancy). One wave streams a
// TWxTH output tile, no block barriers. Per row t: prefetched global load ->
// wave-private LDS row (float2 (p,q)=(a+b,a-b), wave_barrier-ordered) ->
// 11 ds_read_b64/lane -> H-conv (hp,hpp,hq,hqq) -> SHIFT-REGISTER V-conv:
// slot k holds output o=t-10+k; each step adds g[10-k]*h; emits slot 0 when
// t>=10, shifts, zeroes slot 10.
// NOTE: do NOT convert vM/vS to ext_vector float2 — R1 measured 9x WRITE_SIZE
// (scratch spill: 22 loop-carried VGPR-pairs fragment the allocator), VGPR
// dropped 56->40, VALUBusy 53->18%, dur 104->235us. Scalar arrays only.
// TH=32 (L0) / TH=16 (rest): kernel is latency-bound (R0: VALUBusy 53%,
// occ 25%, HBM 11%), so 2-4x wave count beats the +13-40% halo-row overhead.
// EMIT: L0 waves also pool rows pairwise into L1 (a=(P+Q)/2, b=(P-Q)/2).
// ---------------------------------------------------------------------------
template<bool EMIT, int TH>
__device__ __forceinline__ float ssim_wave_tile(
    const float* __restrict__ p1, const float* __restrict__ p2,
    int W, int X0, int Y0, const GW& gw, float2* __restrict__ rb,
    float* __restrict__ o1a, float* __restrict__ o1b, int Wout)
{
    const int lane = threadIdx.x & 63;
    const int gx = X0 + lane;
    const bool cval = gx < W;                              // false only for L4 lanes 32+
    const int hx   = (lane < 5) ? (X0 - 5 + lane) : (X0 + 59 + lane);
    const bool hval = (lane < 10) && ((unsigned)hx < (unsigned)W);
    const int hpos = (lane < 5) ? lane : (64 + lane);      // 0..4 | 69..73
    const int cpos = 5 + lane;

    float vMp[11], vSp[11], vMq[11], vSq[11];
#pragma unroll
    for (int k = 0; k < 11; ++k) { vMp[k] = 0.f; vSp[k] = 0.f; vMq[k] = 0.f; vSq[k] = 0.f; }

    float part = 0.f;
    float pprev = 0.f, qprev = 0.f;
    float a, b, ah, bh;

    auto LOAD = [&](int t, float& oa, float& ob, float& oah, float& obh) {
        int y = Y0 - PAD + t;
        oa = 0.f; ob = 0.f; oah = 0.f; obh = 0.f;
        if ((unsigned)y < (unsigned)W) {
            const float* r1 = p1 + (size_t)y * W;
            const float* r2 = p2 + (size_t)y * W;
            if (cval) { oa  = r1[gx]; ob  = r2[gx]; }
            if (hval) { oah = r1[hx]; obh = r2[hx]; }
        }
    };

    LOAD(0, a, b, ah, bh);

#pragma unroll 2
    for (int t = 0; t < TH + 10; ++t) {
        // prefetch next row while computing this one
        float na, nb, nah, nbh;
        LOAD(t + 1, na, nb, nah, nbh);

        float p = a + b, q = a - b;
        float ph = ah + bh, qh = ah - bh;
        rb[cpos] = make_float2(p, q);
        if (lane < 10) rb[hpos] = make_float2(ph, qh);
        __builtin_amdgcn_wave_barrier();   // writes -> reads (cross-lane RAW)

        float hp = 0.f, hq = 0.f, hpp = 0.f, hqq = 0.f;
#pragma unroll
        for (int j = 0; j < WIN; ++j) {
            float2 v = rb[lane + j];
            float g = gw.g[j];
            hp  = fmaf(g, v.x, hp);
            hpp = fmaf(g, v.x * v.x, hpp);
            hq  = fmaf(g, v.y, hq);
            hqq = fmaf(g, v.y * v.y, hqq);
        }
        __builtin_amdgcn_wave_barrier();   // reads -> next row's writes (WAR)

        // V-conv shift-register accumulate: slot k <- g[10-k]*h (== g[t-o])
#pragma unroll
        for (int k = 0; k < 11; ++k) {
            float g = gw.g[10 - k];
            vMp[k] = fmaf(g, hp,  vMp[k]);
            vSp[k] = fmaf(g, hpp, vSp[k]);
            vMq[k] = fmaf(g, hq,  vMq[k]);
            vSq[k] = fmaf(g, hqq, vSq[k]);
        }

        if (EMIT) {
            if (t >= 6 && t <= TH + 4 && (t & 1) == 0) {   // pool rows (t-1, t)
                float sp_ = p + pprev, sq_ = q + qprev;
                float sp2 = sp_ + __shfl_down(sp_, 1, 64);
                float sq2 = sq_ + __shfl_down(sq_, 1, 64);
                if ((lane & 1) == 0) {
                    float P = sp2 * 0.25f, Q = sq2 * 0.25f;
                    int yo = (t - 6) >> 1;
                    size_t oo = (size_t)((Y0 >> 1) + yo) * Wout + ((X0 >> 1) + (lane >> 1));
                    o1a[oo] = (P + Q) * 0.5f;
                    o1b[oo] = (P - Q) * 0.5f;
                }
            }
            pprev = p; qprev = q;
        }

        if (t >= 10) {                               // output row o = t-10 from slot 0
            int o = t - 10;
            bool yok = (unsigned)(Y0 + o) < (unsigned)W;   // false only for L4 tail
            float Mp = vMp[0], Sp_ = vSp[0], Mq = vMq[0], Sq_ = vSq[0];
            const float C1v = 1e-4f, C2v = 9e-4f;
            float A = Mp * Mp, B = Mq * Mq;
            float ABp = A + B, ABm = A - B;
            float SSp = Sp_ + Sq_, SSm = Sp_ - Sq_;
            float n1 = fmaf(0.5f, ABm, C1v);         // 2*m12 + C1
            float n2 = fmaf(0.5f, SSm - ABm, C2v);   // 2*s12 + C2
            float e1 = fmaf(0.5f, ABp, C1v);         // m1^2+m2^2 + C1
            float e2 = fmaf(0.5f, SSp - ABp, C2v);   // s1+s2 + C2
            float v = (n1 * n2) * __builtin_amdgcn_rcpf(e1 * e2);
            part += (cval && yok) ? v : 0.f;
        }

        // shift down, clear slot 10
#pragma unroll
        for (int k = 0; k < 10; ++k) {
            vMp[k] = vMp[k + 1]; vSp[k] = vSp[k + 1];
            vMq[k] = vMq[k + 1]; vSq[k] = vSq[k + 1];
        }
        vMp[10] = 0.f; vSp[10] = 0.f; vMq[10] = 0.f; vSq[10] = 0.f;

        a = na; b = nb; ah = nah; bh = nbh;
    }

    return part;
}

// ---- L0: 8x16 tiles (64x32) x 48 images = 6144 waves (1536 blocks = 6/CU
//      exactly, single generation at 56 VGPR); emits L1 ----
__global__ __launch_bounds__(256, 4) void ssim_l0_kernel(
    const float* __restrict__ i1, const float* __restrict__ i2,
    float* __restrict__ a1, float* __restrict__ b1,
    double* __restrict__ acc, GW gw)
{
    __shared__ float2 rbs[4][80];
    const int wid = threadIdx.x >> 6;
    const int w = blockIdx.x * 4 + wid;
    const int img = w >> 7;                 // 128 tiles per image
    const int tt = w & 127;
    const int tx = tt & 7, ty = tt >> 3;    // 8 cols x 16 rows
    const size_t off  = (size_t)img * 512 * 512;
    const size_t ooff = (size_t)img * 256 * 256;

    float part = ssim_wave_tile<true, 32>(i1 + off, i2 + off, 512, tx * 64, ty * 32,
                                          gw, rbs[wid], a1 + ooff, b1 + ooff, 256);
#pragma unroll
    for (int o = 32; o > 0; o >>= 1) part += __shfl_down(part, o, 64);
    if ((threadIdx.x & 63) == 0) atomicAdd(acc, (double)part);
}

// ---- L1..L4 with 64x16 tiles: 64+16+4+2 = 86 tiles/image = 4128 waves
//      (1032 blocks ~ 4/CU resident in one generation) ----
__global__ __launch_bounds__(256, 4) void ssim_rest_kernel(
    const float* __restrict__ a1, const float* __restrict__ b1,
    const float* __restrict__ a2, const float* __restrict__ b2,
    const float* __restrict__ a3, const float* __restrict__ b3,
    const float* __restrict__ a4, const float* __restrict__ b4,
    double* __restrict__ acc, GW gw)
{
    __shared__ float2 rbs[4][80];
    const int wid = threadIdx.x >> 6;
    const int w = blockIdx.x * 4 + wid;
    const int img = w / 86;
    const int r = w - img * 86;
    int lvl, tx, ty;
    if (r < 64)      { lvl = 1; tx = r & 3;  ty = r >> 2; }                // 4x16
    else if (r < 80) { lvl = 2; int s = r - 64; tx = s & 1; ty = s >> 1; } // 2x8
    else if (r < 84) { lvl = 3; tx = 0; ty = r - 80; }                     // 1x4
    else             { lvl = 4; tx = 0; ty = r - 84; }                     // 1x2
    const int W = 512 >> lvl;
    const float* p1; const float* p2;
    switch (lvl) {
      case 1:  p1 = a1; p2 = b1; break;
      case 2:  p1 = a2; p2 = b2; break;
      case 3:  p1 = a3; p2 = b3; break;
      default: p1 = a4; p2 = b4; break;
    }
    const size_t off = (size_t)img * W * W;

    float part = ssim_wave_tile<false, 16>(p1 + off, p2 + off, W, tx * 64, ty * 16,
                                           gw, rbs[wid], nullptr, nullptr, 0);
#pragma unroll
    for (int o = 32; o > 0; o >>= 1) part += __shfl_down(part, o, 64);
    if ((threadIdx.x & 63) == 0) atomicAdd(acc + lvl, (double)part);
}

// ---- pool L1 -> L2/L3/L4. Grid (16, 96). ----
__global__ __launch_bounds__(256) void pool_rest_kernel(
    const float* __restrict__ a1, const float* __restrict__ b1,
    float* __restrict__ a2, float* __restrict__ b2,
    float* __restrict__ a3, float* __restrict__ b3,
    float* __restrict__ a4, float* __restrict__ b4)
{
    __shared__ float l2[32][33];
    __shared__ float l3[16][17];
    const int tid = threadIdx.x;
    const int im = blockIdx.y;
    const int tb = blockIdx.x;
    const int tx = tb & 3, ty = tb >> 2;
    const bool second = im >= 48;
    const int ii = second ? im - 48 : im;
    const float* src = (second ? b1 : a1) + (size_t)ii * 256 * 256;
    float* o2 = (second ? b2 : a2) + (size_t)ii * 128 * 128;
    float* o3 = (second ? b3 : a3) + (size_t)ii * 64 * 64;
    float* o4 = (second ? b4 : a4) + (size_t)ii * 32 * 32;
    const int X0 = tx * 64, Y0 = ty * 64;

#pragma unroll
    for (int k = 0; k < 2; ++k) {
        int idx = tid + k * 256;
        int xp = idx & 15;
        int yo = idx >> 4;
        const float* rp = src + (size_t)(Y0 + 2 * yo) * 256 + (X0 + 4 * xp);
        float4 r0 = *(const float4*)rp;
        float4 r1 = *(const float4*)(rp + 256);
        float v0 = (r0.x + r0.y + r1.x + r1.y) * 0.25f;
        float v1 = (r0.z + r0.w + r1.z + r1.w) * 0.25f;
        l2[yo][2 * xp]     = v0;
        l2[yo][2 * xp + 1] = v1;
        float2* op = (float2*)(o2 + (size_t)((Y0 >> 1) + yo) * 128 + ((X0 >> 1) + 2 * xp));
        *op = make_float2(v0, v1);
    }
    __syncthreads();
    {
        int xo = tid & 15, yo = tid >> 4;
        if (yo < 16) {
            float v = (l2[2*yo][2*xo] + l2[2*yo][2*xo+1] +
                       l2[2*yo+1][2*xo] + l2[2*yo+1][2*xo+1]) * 0.25f;
            l3[yo][xo] = v;
            o3[(size_t)((Y0 >> 2) + yo) * 64 + ((X0 >> 2) + xo)] = v;
        }
    }
    __syncthreads();
    if (tid < 64) {
        int xo = tid & 7, yo = tid >> 3;
        float v = (l3[2*yo][2*xo] + l3[2*yo][2*xo+1] +
                   l3[2*yo+1][2*xo] + l3[2*yo+1][2*xo+1]) * 0.25f;
        o4[(size_t)((Y0 >> 3) + yo) * 32 + ((X0 >> 3) + xo)] = v;
    }
}

__global__ void final_kernel(const double* __restrict__ acc, float* __restrict__ out)
{
    double loss = 0.0;
#pragma unroll
    for (int l = 0; l < 5; ++l) {
        double cnt = 48.0 * (double)(512 >> l) * (double)(512 >> l);
        loss += 1.0 - acc[l] / cnt;
    }
    out[0] = (float)loss;
}

extern "C" void kernel_launch(void* const* d_in, const int* in_sizes, int n_in,
                              void* d_out, int out_size, void* d_ws, size_t ws_size,
                              hipStream_t stream)
{
    const float* img1 = (const float*)d_in[0];
    const float* img2 = (const float*)d_in[1];
    float* out = (float*)d_out;

    // 1D gaussian (sigma=1.5, k=11), matches reference construction
    GW gw;
    double gs[WIN], sum = 0.0;
    for (int i = 0; i < WIN; ++i) {
        double ax = (double)i - 5.0;
        gs[i] = exp(-(ax * ax) / 4.5);
        sum += gs[i];
    }
    for (int i = 0; i < WIN; ++i) gw.g[i] = (float)(gs[i] / sum);

    // workspace: 64B header (5 double acc), then pyramid
    double* acc = (double*)d_ws;
    float* base = (float*)((char*)d_ws + 64);
    const size_t n1 = 48ull * 256 * 256;
    const size_t n2 = 48ull * 128 * 128;
    const size_t n3 = 48ull * 64 * 64;
    const size_t n4 = 48ull * 32 * 32;
    float* a1 = base;      float* b1 = a1 + n1;
    float* a2 = b1 + n1;   float* b2 = a2 + n2;
    float* a3 = b2 + n2;   float* b3 = a3 + n3;
    float* a4 = b3 + n3;   float* b4 = a4 + n4;

    hipMemsetAsync(acc, 0, 5 * sizeof(double), stream);

    hipLaunchKernelGGL(ssim_l0_kernel, dim3(1536), dim3(256), 0, stream,
                       img1, img2, a1, b1, acc, gw);

    hipLaunchKernelGGL(pool_rest_kernel, dim3(16, 96), dim3(256), 0, stream,
                       a1, b1, a2, b2, a3, b3, a4, b4);

    hipLaunchKernelGGL(ssim_rest_kernel, dim3(1032), dim3(256), 0, stream,
                       a1, b1, a2, b2, a3, b3, a4, b4, acc, gw);

    hipLaunchKernelGGL(final_kernel, dim3(1), dim3(1), 0, stream, acc, out);
}

// Round 3
// 298.847 us; speedup vs baseline: 1.5045x; 1.0175x over previous
//
#include <hip/hip_runtime.h>
#include <math.h>

#define WIN 11
#define PAD 5
#define TW 64              // tile width = wave width

typedef float v2f __attribute__((ext_vector_type(2)));

struct GW { float g[WIN]; };

// ---------------------------------------------------------------------------
// Wave-autonomous SSIM tile. One wave streams a TWxTH output tile, no block
// barriers. Per row t:
//   depth-2 prefetched global load (kills the per-row vmcnt stall: the batch
//   consumed at row t was issued at row t-2, ~2 full row-bodies of covering
//   work vs ~900cy HBM latency) ->
//   wave-private LDS row of float4 (p, q, p^2, q^2) — squares computed ONCE
//   at write time instead of 11x at read time ->
//   11 ds_read_b128/lane + packed H-conv: hM=(hp,hq), hS=(hpp,hqq) via
//   v_pk_fma_f32 (2 transient pairs only — NOT the R1 spill trap, which was
//   22 loop-carried pairs; accumulators below stay scalar) ->
//   scalar SHIFT-REGISTER V-conv: slot k holds output o=t-10+k; each step
//   adds g[10-k]*h; emits slot 0 when t>=10, shifts, zeroes slot 10.
// NOTE: VGPR must stay <=64 (waves/SIMD halve at the 64-VGPR cliff, m69).
// R2 measured: per-SIMD wave-row service ~1150cy at 50% VALUBusy regardless
// of 3 vs 6 resident waves -> latency-serialized per wave, not wave-starved.
// EMIT: L0 waves also pool rows pairwise into L1 (a=(P+Q)/2, b=(P-Q)/2).
// ---------------------------------------------------------------------------
template<bool EMIT, int TH>
__device__ __forceinline__ float ssim_wave_tile(
    const float* __restrict__ p1, const float* __restrict__ p2,
    int W, int X0, int Y0, const GW& gw, float4* __restrict__ rb,
    float* __restrict__ o1a, float* __restrict__ o1b, int Wout)
{
    const int lane = threadIdx.x & 63;
    const int gx = X0 + lane;
    const bool cval = gx < W;                              // false only for L4 lanes 32+
    const int hx   = (lane < 5) ? (X0 - 5 + lane) : (X0 + 59 + lane);
    const bool hval = (lane < 10) && ((unsigned)hx < (unsigned)W);
    const int hpos = (lane < 5) ? lane : (64 + lane);      // 0..4 | 69..73
    const int cpos = 5 + lane;

    float vMp[11], vSp[11], vMq[11], vSq[11];
#pragma unroll
    for (int k = 0; k < 11; ++k) { vMp[k] = 0.f; vSp[k] = 0.f; vMq[k] = 0.f; vSq[k] = 0.f; }

    float part = 0.f;
    float pprev = 0.f, qprev = 0.f;

    auto LOAD = [&](int t, float& oa, float& ob, float& oah, float& obh) {
        int y = Y0 - PAD + t;
        oa = 0.f; ob = 0.f; oah = 0.f; obh = 0.f;
        if ((unsigned)y < (unsigned)W) {
            const float* r1 = p1 + (size_t)y * W;
            const float* r2 = p2 + (size_t)y * W;
            if (cval) { oa  = r1[gx]; ob  = r2[gx]; }
            if (hval) { oah = r1[hx]; obh = r2[hx]; }
        }
    };

    // depth-2 prefetch pipeline: row t in (a0..), t+1 in (a1..)
    float a0, b0, ah0, bh0;
    float a1, b1, ah1, bh1;
    LOAD(0, a0, b0, ah0, bh0);
    LOAD(1, a1, b1, ah1, bh1);

#pragma unroll 2
    for (int t = 0; t < TH + 10; ++t) {
        // issue row t+2 now; it's consumed two full row-bodies from now
        float a2, b2, ah2, bh2;
        LOAD(t + 2, a2, b2, ah2, bh2);

        float p = a0 + b0, q = a0 - b0;
        rb[cpos] = make_float4(p, q, p * p, q * q);
        if (lane < 10) {
            float ph = ah0 + bh0, qh = ah0 - bh0;
            rb[hpos] = make_float4(ph, qh, ph * ph, qh * qh);
        }
        __builtin_amdgcn_wave_barrier();   // writes -> reads (cross-lane RAW)

        v2f hM = {0.f, 0.f}, hS = {0.f, 0.f};
#pragma unroll
        for (int j = 0; j < WIN; ++j) {
            float4 v = rb[lane + j];
            v2f vm = { v.x, v.y };
            v2f vs = { v.z, v.w };
            v2f g2 = { gw.g[j], gw.g[j] };
            hM = __builtin_elementwise_fma(g2, vm, hM);
            hS = __builtin_elementwise_fma(g2, vs, hS);
        }
        __builtin_amdgcn_wave_barrier();   // reads -> next row's writes (WAR)
        float hp = hM.x, hq = hM.y, hpp = hS.x, hqq = hS.y;

        // V-conv shift-register accumulate: slot k <- g[10-k]*h (== g[t-o])
#pragma unroll
        for (int k = 0; k < 11; ++k) {
            float g = gw.g[10 - k];
            vMp[k] = fmaf(g, hp,  vMp[k]);
            vSp[k] = fmaf(g, hpp, vSp[k]);
            vMq[k] = fmaf(g, hq,  vMq[k]);
            vSq[k] = fmaf(g, hqq, vSq[k]);
        }

        if (EMIT) {
            if (t >= 6 && t <= TH + 4 && (t & 1) == 0) {   // pool rows (t-1, t)
                float sp_ = p + pprev, sq_ = q + qprev;
                float sp2 = sp_ + __shfl_down(sp_, 1, 64);
                float sq2 = sq_ + __shfl_down(sq_, 1, 64);
                if ((lane & 1) == 0) {
                    float P = sp2 * 0.25f, Q = sq2 * 0.25f;
                    int yo = (t - 6) >> 1;
                    size_t oo = (size_t)((Y0 >> 1) + yo) * Wout + ((X0 >> 1) + (lane >> 1));
                    o1a[oo] = (P + Q) * 0.5f;
                    o1b[oo] = (P - Q) * 0.5f;
                }
            }
            pprev = p; qprev = q;
        }

        if (t >= 10) {                               // output row o = t-10 from slot 0
            int o = t - 10;
            bool yok = (unsigned)(Y0 + o) < (unsigned)W;   // false only for L4 tail
            float Mp = vMp[0], Sp_ = vSp[0], Mq = vMq[0], Sq_ = vSq[0];
            const float C1v = 1e-4f, C2v = 9e-4f;
            float A = Mp * Mp, B = Mq * Mq;
            float ABp = A + B, ABm = A - B;
            float SSp = Sp_ + Sq_, SSm = Sp_ - Sq_;
            float n1 = fmaf(0.5f, ABm, C1v);         // 2*m12 + C1
            float n2 = fmaf(0.5f, SSm - ABm, C2v);   // 2*s12 + C2
            float e1 = fmaf(0.5f, ABp, C1v);         // m1^2+m2^2 + C1
            float e2 = fmaf(0.5f, SSp - ABp, C2v);   // s1+s2 + C2
            float v = (n1 * n2) * __builtin_amdgcn_rcpf(e1 * e2);
            part += (cval && yok) ? v : 0.f;
        }

        // shift down, clear slot 10
#pragma unroll
        for (int k = 0; k < 10; ++k) {
            vMp[k] = vMp[k + 1]; vSp[k] = vSp[k + 1];
            vMq[k] = vMq[k + 1]; vSq[k] = vSq[k + 1];
        }
        vMp[10] = 0.f; vSp[10] = 0.f; vMq[10] = 0.f; vSq[10] = 0.f;

        // rotate prefetch pipeline (renamed away by unroll-2)
        a0 = a1; b0 = b1; ah0 = ah1; bh0 = bh1;
        a1 = a2; b1 = b2; ah1 = ah2; bh1 = bh2;
    }

    return part;
}

// ---- L0: 8x16 tiles (64x32) x 48 images = 6144 waves (1536 blocks); emits L1 ----
__global__ __launch_bounds__(256, 4) void ssim_l0_kernel(
    const float* __restrict__ i1, const float* __restrict__ i2,
    float* __restrict__ a1, float* __restrict__ b1,
    double* __restrict__ acc, GW gw)
{
    __shared__ float4 rbs[4][80];
    const int wid = threadIdx.x >> 6;
    const int w = blockIdx.x * 4 + wid;
    const int img = w >> 7;                 // 128 tiles per image
    const int tt = w & 127;
    const int tx = tt & 7, ty = tt >> 3;    // 8 cols x 16 rows
    const size_t off  = (size_t)img * 512 * 512;
    const size_t ooff = (size_t)img * 256 * 256;

    float part = ssim_wave_tile<true, 32>(i1 + off, i2 + off, 512, tx * 64, ty * 32,
                                          gw, rbs[wid], a1 + ooff, b1 + ooff, 256);
#pragma unroll
    for (int o = 32; o > 0; o >>= 1) part += __shfl_down(part, o, 64);
    if ((threadIdx.x & 63) == 0) atomicAdd(acc, (double)part);
}

// ---- L1..L4 with 64x16 tiles: 64+16+4+2 = 86 tiles/image = 4128 waves ----
__global__ __launch_bounds__(256, 4) void ssim_rest_kernel(
    const float* __restrict__ a1, const float* __restrict__ b1,
    const float* __restrict__ a2, const float* __restrict__ b2,
    const float* __restrict__ a3, const float* __restrict__ b3,
    const float* __restrict__ a4, const float* __restrict__ b4,
    double* __restrict__ acc, GW gw)
{
    __shared__ float4 rbs[4][80];
    const int wid = threadIdx.x >> 6;
    const int w = blockIdx.x * 4 + wid;
    const int img = w / 86;
    const int r = w - img * 86;
    int lvl, tx, ty;
    if (r < 64)      { lvl = 1; tx = r & 3;  ty = r >> 2; }                // 4x16
    else if (r < 80) { lvl = 2; int s = r - 64; tx = s & 1; ty = s >> 1; } // 2x8
    else if (r < 84) { lvl = 3; tx = 0; ty = r - 80; }                     // 1x4
    else             { lvl = 4; tx = 0; ty = r - 84; }                     // 1x2
    const int W = 512 >> lvl;
    const float* p1; const float* p2;
    switch (lvl) {
      case 1:  p1 = a1; p2 = b1; break;
      case 2:  p1 = a2; p2 = b2; break;
      case 3:  p1 = a3; p2 = b3; break;
      default: p1 = a4; p2 = b4; break;
    }
    const size_t off = (size_t)img * W * W;

    float part = ssim_wave_tile<false, 16>(p1 + off, p2 + off, W, tx * 64, ty * 16,
                                           gw, rbs[wid], nullptr, nullptr, 0);
#pragma unroll
    for (int o = 32; o > 0; o >>= 1) part += __shfl_down(part, o, 64);
    if ((threadIdx.x & 63) == 0) atomicAdd(acc + lvl, (double)part);
}

// ---- pool L1 -> L2/L3/L4. Grid (16, 96). ----
__global__ __launch_bounds__(256) void pool_rest_kernel(
    const float* __restrict__ a1, const float* __restrict__ b1,
    float* __restrict__ a2, float* __restrict__ b2,
    float* __restrict__ a3, float* __restrict__ b3,
    float* __restrict__ a4, float* __restrict__ b4)
{
    __shared__ float l2[32][33];
    __shared__ float l3[16][17];
    const int tid = threadIdx.x;
    const int im = blockIdx.y;
    const int tb = blockIdx.x;
    const int tx = tb & 3, ty = tb >> 2;
    const bool second = im >= 48;
    const int ii = second ? im - 48 : im;
    const float* src = (second ? b1 : a1) + (size_t)ii * 256 * 256;
    float* o2 = (second ? b2 : a2) + (size_t)ii * 128 * 128;
    float* o3 = (second ? b3 : a3) + (size_t)ii * 64 * 64;
    float* o4 = (second ? b4 : a4) + (size_t)ii * 32 * 32;
    const int X0 = tx * 64, Y0 = ty * 64;

#pragma unroll
    for (int k = 0; k < 2; ++k) {
        int idx = tid + k * 256;
        int xp = idx & 15;
        int yo = idx >> 4;
        const float* rp = src + (size_t)(Y0 + 2 * yo) * 256 + (X0 + 4 * xp);
        float4 r0 = *(const float4*)rp;
        float4 r1 = *(const float4*)(rp + 256);
        float v0 = (r0.x + r0.y + r1.x + r1.y) * 0.25f;
        float v1 = (r0.z + r0.w + r1.z + r1.w) * 0.25f;
        l2[yo][2 * xp]     = v0;
        l2[yo][2 * xp + 1] = v1;
        float2* op = (float2*)(o2 + (size_t)((Y0 >> 1) + yo) * 128 + ((X0 >> 1) + 2 * xp));
        *op = make_float2(v0, v1);
    }
    __syncthreads();
    {
        int xo = tid & 15, yo = tid >> 4;
        if (yo < 16) {
            float v = (l2[2*yo][2*xo] + l2[2*yo][2*xo+1] +
                       l2[2*yo+1][2*xo] + l2[2*yo+1][2*xo+1]) * 0.25f;
            l3[yo][xo] = v;
            o3[(size_t)((Y0 >> 2) + yo) * 64 + ((X0 >> 2) + xo)] = v;
        }
    }
    __syncthreads();
    if (tid < 64) {
        int xo = tid & 7, yo = tid >> 3;
        float v = (l3[2*yo][2*xo] + l3[2*yo][2*xo+1] +
                   l3[2*yo+1][2*xo] + l3[2*yo+1][2*xo+1]) * 0.25f;
        o4[(size_t)((Y0 >> 3) + yo) * 32 + ((X0 >> 3) + xo)] = v;
    }
}

__global__ void final_kernel(const double* __restrict__ acc, float* __restrict__ out)
{
    double loss = 0.0;
#pragma unroll
    for (int l = 0; l < 5; ++l) {
        double cnt = 48.0 * (double)(512 >> l) * (double)(512 >> l);
        loss += 1.0 - acc[l] / cnt;
    }
    out[0] = (float)loss;
}

extern "C" void kernel_launch(void* const* d_in, const int* in_sizes, int n_in,
                              void* d_out, int out_size, void* d_ws, size_t ws_size,
                              hipStream_t stream)
{
    const float* img1 = (const float*)d_in[0];
    const float* img2 = (const float*)d_in[1];
    float* out = (float*)d_out;

    // 1D gaussian (sigma=1.5, k=11), matches reference construction
    GW gw;
    double gs[WIN], sum = 0.0;
    for (int i = 0; i < WIN; ++i) {
        double ax = (double)i - 5.0;
        gs[i] = exp(-(ax * ax) / 4.5);
        sum += gs[i];
    }
    for (int i = 0; i < WIN; ++i) gw.g[i] = (float)(gs[i] / sum);

    // workspace: 64B header (5 double acc), then pyramid
    double* acc = (double*)d_ws;
    float* base = (float*)((char*)d_ws + 64);
    const size_t n1 = 48ull * 256 * 256;
    const size_t n2 = 48ull * 128 * 128;
    const size_t n3 = 48ull * 64 * 64;
    const size_t n4 = 48ull * 32 * 32;
    float* a1 = base;      float* b1 = a1 + n1;
    float* a2 = b1 + n1;   float* b2 = a2 + n2;
    float* a3 = b2 + n2;   float* b3 = a3 + n3;
    float* a4 = b3 + n3;   float* b4 = a4 + n4;

    hipMemsetAsync(acc, 0, 5 * sizeof(double), stream);

    hipLaunchKernelGGL(ssim_l0_kernel, dim3(1536), dim3(256), 0, stream,
                       img1, img2, a1, b1, acc, gw);

    hipLaunchKernelGGL(pool_rest_kernel, dim3(16, 96), dim3(256), 0, stream,
                       a1, b1, a2, b2, a3, b3, a4, b4);

    hipLaunchKernelGGL(ssim_rest_kernel, dim3(264 * 4 / 4 == 264 ? 1032 : 1032), dim3(256), 0, stream,
                       a1, b1, a2, b2, a3, b3, a4, b4, acc, gw);

    hipLaunchKernelGGL(final_kernel, dim3(1), dim3(1), 0, stream, acc, out);
}

// Round 4
// 277.852 us; speedup vs baseline: 1.6182x; 1.0756x over previous
//
#include <hip/hip_runtime.h>
#include <math.h>

#define WIN 11
#define PAD 5
#define TW 64              // tile width = wave width

typedef float v2f __attribute__((ext_vector_type(2)));

struct GW { float g[WIN]; };

// ---------------------------------------------------------------------------
// Wave-autonomous SSIM tile, STATIC-RING edition. One wave streams a 64xTH
// output tile, no block barriers. Per row t:
//   depth-2 prefetched global load (vmcnt stall covered by 2 row-bodies) ->
//   wave-private LDS row of float2 (p,q) (float4 removed: R3 measured it at
//   ~93% of the 256 B/cyc LDS read ceiling; float2 halves the traffic) ->
//   11 ds_read_b64 + packed H-conv (1 pk_mul for squares + 2 pk_fma per tap) ->
//   V-conv STATIC RING (the R3 shift-register spent ~40 v_mov/row; here the
//   t-loop is unrolled by 11 so slot roles rotate at compile time, zero movs):
//   row t, slot s: weight g[10 - ((s - t) mod 11)]; slot s == t%11 completes
//   output o = t-10 (guarded o<TH), emits, zeroes.
// sched_barrier(0) at each row boundary pins loads to their row — prevents
// the unroll-hoist spill disaster (R8: 975 MB scratch) while keeping the
// depth-2 prefetch distance. Accumulators are SCALAR float[11] with static
// indices only (R1 measured: 22 loop-carried v2f pairs -> spill, 9x WRITE).
// NROWS = 44 (4 x 11) covers TH=32 (+2 waste rows, guarded).
// EMIT: L0 waves also pool rows pairwise into L1 (a=(P+Q)/2, b=(P-Q)/2).
// ---------------------------------------------------------------------------
template<bool EMIT>
__device__ __forceinline__ float ssim_wave_tile(
    const float* __restrict__ p1, const float* __restrict__ p2,
    int W, int X0, int Y0, const GW& gw, float2* __restrict__ rb,
    float* __restrict__ o1a, float* __restrict__ o1b, int Wout)
{
    const int TH = 32;
    const int lane = threadIdx.x & 63;
    const int gx = X0 + lane;
    const bool cval = gx < W;                              // false only for L4 lanes 32+
    const int hx   = (lane < 5) ? (X0 - 5 + lane) : (X0 + 59 + lane);
    const bool hval = (lane < 10) && ((unsigned)hx < (unsigned)W);
    const int hpos = (lane < 5) ? lane : (64 + lane);      // 0..4 | 69..73
    const int cpos = 5 + lane;

    float vMp[11], vSp[11], vMq[11], vSq[11];
#pragma unroll
    for (int k = 0; k < 11; ++k) { vMp[k] = 0.f; vSp[k] = 0.f; vMq[k] = 0.f; vSq[k] = 0.f; }

    float part = 0.f;
    float pprev = 0.f, qprev = 0.f;

    auto LOAD = [&](int t, float& oa, float& ob, float& oah, float& obh) {
        int y = Y0 - PAD + t;
        oa = 0.f; ob = 0.f; oah = 0.f; obh = 0.f;
        if ((unsigned)y < (unsigned)W) {
            const float* r1 = p1 + (size_t)y * W;
            const float* r2 = p2 + (size_t)y * W;
            if (cval) { oa  = r1[gx]; ob  = r2[gx]; }
            if (hval) { oah = r1[hx]; obh = r2[hx]; }
        }
    };

    // depth-2 prefetch pipeline: row t in (a0..), t+1 in (a1..)
    float a0, b0, ah0, bh0;
    float a1, b1, ah1, bh1;
    LOAD(0, a0, b0, ah0, bh0);
    LOAD(1, a1, b1, ah1, bh1);

#pragma unroll 1
    for (int blk = 0; blk < 4; ++blk) {
#pragma unroll
        for (int u = 0; u < 11; ++u) {
            const int t = blk * 11 + u;        // u compile-time, blk runtime

            // issue row t+2 now; consumed two full row-bodies from now
            float a2, b2, ah2, bh2;
            LOAD(t + 2, a2, b2, ah2, bh2);

            float p = a0 + b0, q = a0 - b0;
            rb[cpos] = make_float2(p, q);
            if (lane < 10) {
                float ph = ah0 + bh0, qh = ah0 - bh0;
                rb[hpos] = make_float2(ph, qh);
            }
            __builtin_amdgcn_wave_barrier();   // writes -> reads (cross-lane RAW)

            v2f hM = {0.f, 0.f}, hS = {0.f, 0.f};
#pragma unroll
            for (int j = 0; j < WIN; ++j) {
                float2 v = rb[lane + j];
                v2f vm = { v.x, v.y };
                v2f g2 = { gw.g[j], gw.g[j] };
                hM = __builtin_elementwise_fma(g2, vm, hM);
                hS = __builtin_elementwise_fma(g2, vm * vm, hS);
            }
            __builtin_amdgcn_wave_barrier();   // reads -> next row's writes (WAR)
            float hp = hM.x, hq = hM.y, hpp = hS.x, hqq = hS.y;

            // V-conv static ring: slot s, row t: weight g[10 - ((s-t) mod 11)]
#pragma unroll
            for (int s = 0; s < 11; ++s) {
                const int widx = 10 - ((s - u + 11) % 11);
                float g = gw.g[widx];
                vMp[s] = fmaf(g, hp,  vMp[s]);
                vSp[s] = fmaf(g, hpp, vSp[s]);
                vMq[s] = fmaf(g, hq,  vMq[s]);
                vSq[s] = fmaf(g, hqq, vSq[s]);
            }

            if (EMIT) {
                if (t >= 6 && t <= TH + 4 && (t & 1) == 0) {   // pool rows (t-1, t)
                    float sp_ = p + pprev, sq_ = q + qprev;
                    float sp2 = sp_ + __shfl_down(sp_, 1, 64);
                    float sq2 = sq_ + __shfl_down(sq_, 1, 64);
                    if ((lane & 1) == 0) {
                        float P = sp2 * 0.25f, Q = sq2 * 0.25f;
                        int yo = (t - 6) >> 1;
                        size_t oo = (size_t)((Y0 >> 1) + yo) * Wout + ((X0 >> 1) + (lane >> 1));
                        o1a[oo] = (P + Q) * 0.5f;
                        o1b[oo] = (P - Q) * 0.5f;
                    }
                }
                pprev = p; qprev = q;
            }

            // slot u completes output o = t-10 this row (after its g[10] tap)
            {
                int o = t - 10;
                if ((unsigned)o < (unsigned)TH) {
                    bool yok = (unsigned)(Y0 + o) < (unsigned)W;   // false only for L4 tail
                    float Mp = vMp[u], Sp_ = vSp[u], Mq = vMq[u], Sq_ = vSq[u];
                    const float C1v = 1e-4f, C2v = 9e-4f;
                    float A = Mp * Mp, B = Mq * Mq;
                    float ABp = A + B, ABm = A - B;
                    float SSp = Sp_ + Sq_, SSm = Sp_ - Sq_;
                    float n1 = fmaf(0.5f, ABm, C1v);         // 2*m12 + C1
                    float n2 = fmaf(0.5f, SSm - ABm, C2v);   // 2*s12 + C2
                    float e1 = fmaf(0.5f, ABp, C1v);         // m1^2+m2^2 + C1
                    float e2 = fmaf(0.5f, SSp - ABp, C2v);   // s1+s2 + C2
                    float v = (n1 * n2) * __builtin_amdgcn_rcpf(e1 * e2);
                    part += (cval && yok) ? v : 0.f;
                }
                vMp[u] = 0.f; vSp[u] = 0.f; vMq[u] = 0.f; vSq[u] = 0.f;
            }

            // rotate prefetch pipeline
            a0 = a1; b0 = b1; ah0 = ah1; bh0 = bh1;
            a1 = a2; b1 = b2; ah1 = ah2; bh1 = bh2;

            // pin row boundary: no load hoisting / cross-row motion (R8 trap)
            __builtin_amdgcn_sched_barrier(0);
        }
    }

    return part;
}

// ---- L0: 8x16 tiles (64x32) x 48 images = 6144 waves (1536 blocks); emits L1 ----
__global__ __launch_bounds__(256, 4) void ssim_l0_kernel(
    const float* __restrict__ i1, const float* __restrict__ i2,
    float* __restrict__ a1, float* __restrict__ b1,
    double* __restrict__ acc, GW gw)
{
    __shared__ float2 rbs[4][80];
    const int wid = threadIdx.x >> 6;
    const int w = blockIdx.x * 4 + wid;
    const int img = w >> 7;                 // 128 tiles per image
    const int tt = w & 127;
    const int tx = tt & 7, ty = tt >> 3;    // 8 cols x 16 rows
    const size_t off  = (size_t)img * 512 * 512;
    const size_t ooff = (size_t)img * 256 * 256;

    float part = ssim_wave_tile<true>(i1 + off, i2 + off, 512, tx * 64, ty * 32,
                                      gw, rbs[wid], a1 + ooff, b1 + ooff, 256);
#pragma unroll
    for (int o = 32; o > 0; o >>= 1) part += __shfl_down(part, o, 64);
    if ((threadIdx.x & 63) == 0) atomicAdd(acc, (double)part);
}

// ---- L1..L4, all 64x32 tiles: 32+8+2+1 = 43 tiles/image = 2064 waves
//      (516 blocks). TH=32 cuts halo overhead to 1.31 rows/output. ----
__global__ __launch_bounds__(256, 4) void ssim_rest_kernel(
    const float* __restrict__ a1, const float* __restrict__ b1,
    const float* __restrict__ a2, const float* __restrict__ b2,
    const float* __restrict__ a3, const float* __restrict__ b3,
    const float* __restrict__ a4, const float* __restrict__ b4,
    double* __restrict__ acc, GW gw)
{
    __shared__ float2 rbs[4][80];
    const int wid = threadIdx.x >> 6;
    const int w = blockIdx.x * 4 + wid;
    const int img = w / 43;
    const int r = w - img * 43;
    int lvl, tx, ty;
    if (r < 32)      { lvl = 1; tx = r & 3;  ty = r >> 2; }                // 4x8
    else if (r < 40) { lvl = 2; int s = r - 32; tx = s & 1; ty = s >> 1; } // 2x4
    else if (r < 42) { lvl = 3; tx = 0; ty = r - 40; }                     // 1x2
    else             { lvl = 4; tx = 0; ty = 0; }                          // 1x1
    const int W = 512 >> lvl;
    const float* p1; const float* p2;
    switch (lvl) {
      case 1:  p1 = a1; p2 = b1; break;
      case 2:  p1 = a2; p2 = b2; break;
      case 3:  p1 = a3; p2 = b3; break;
      default: p1 = a4; p2 = b4; break;
    }
    const size_t off = (size_t)img * W * W;

    float part = ssim_wave_tile<false>(p1 + off, p2 + off, W, tx * 64, ty * 32,
                                       gw, rbs[wid], nullptr, nullptr, 0);
#pragma unroll
    for (int o = 32; o > 0; o >>= 1) part += __shfl_down(part, o, 64);
    if ((threadIdx.x & 63) == 0) atomicAdd(acc + lvl, (double)part);
}

// ---- pool L1 -> L2/L3/L4. Grid (16, 96). ----
__global__ __launch_bounds__(256) void pool_rest_kernel(
    const float* __restrict__ a1, const float* __restrict__ b1,
    float* __restrict__ a2, float* __restrict__ b2,
    float* __restrict__ a3, float* __restrict__ b3,
    float* __restrict__ a4, float* __restrict__ b4)
{
    __shared__ float l2[32][33];
    __shared__ float l3[16][17];
    const int tid = threadIdx.x;
    const int im = blockIdx.y;
    const int tb = blockIdx.x;
    const int tx = tb & 3, ty = tb >> 2;
    const bool second = im >= 48;
    const int ii = second ? im - 48 : im;
    const float* src = (second ? b1 : a1) + (size_t)ii * 256 * 256;
    float* o2 = (second ? b2 : a2) + (size_t)ii * 128 * 128;
    float* o3 = (second ? b3 : a3) + (size_t)ii * 64 * 64;
    float* o4 = (second ? b4 : a4) + (size_t)ii * 32 * 32;
    const int X0 = tx * 64, Y0 = ty * 64;

#pragma unroll
    for (int k = 0; k < 2; ++k) {
        int idx = tid + k * 256;
        int xp = idx & 15;
        int yo = idx >> 4;
        const float* rp = src + (size_t)(Y0 + 2 * yo) * 256 + (X0 + 4 * xp);
        float4 r0 = *(const float4*)rp;
        float4 r1 = *(const float4*)(rp + 256);
        float v0 = (r0.x + r0.y + r1.x + r1.y) * 0.25f;
        float v1 = (r0.z + r0.w + r1.z + r1.w) * 0.25f;
        l2[yo][2 * xp]     = v0;
        l2[yo][2 * xp + 1] = v1;
        float2* op = (float2*)(o2 + (size_t)((Y0 >> 1) + yo) * 128 + ((X0 >> 1) + 2 * xp));
        *op = make_float2(v0, v1);
    }
    __syncthreads();
    {
        int xo = tid & 15, yo = tid >> 4;
        if (yo < 16) {
            float v = (l2[2*yo][2*xo] + l2[2*yo][2*xo+1] +
                       l2[2*yo+1][2*xo] + l2[2*yo+1][2*xo+1]) * 0.25f;
            l3[yo][xo] = v;
            o3[(size_t)((Y0 >> 2) + yo) * 64 + ((X0 >> 2) + xo)] = v;
        }
    }
    __syncthreads();
    if (tid < 64) {
        int xo = tid & 7, yo = tid >> 3;
        float v = (l3[2*yo][2*xo] + l3[2*yo][2*xo+1] +
                   l3[2*yo+1][2*xo] + l3[2*yo+1][2*xo+1]) * 0.25f;
        o4[(size_t)((Y0 >> 3) + yo) * 32 + ((X0 >> 3) + xo)] = v;
    }
}

__global__ void final_kernel(const double* __restrict__ acc, float* __restrict__ out)
{
    double loss = 0.0;
#pragma unroll
    for (int l = 0; l < 5; ++l) {
        double cnt = 48.0 * (double)(512 >> l) * (double)(512 >> l);
        loss += 1.0 - acc[l] / cnt;
    }
    out[0] = (float)loss;
}

extern "C" void kernel_launch(void* const* d_in, const int* in_sizes, int n_in,
                              void* d_out, int out_size, void* d_ws, size_t ws_size,
                              hipStream_t stream)
{
    const float* img1 = (const float*)d_in[0];
    const float* img2 = (const float*)d_in[1];
    float* out = (float*)d_out;

    // 1D gaussian (sigma=1.5, k=11), matches reference construction
    GW gw;
    double gs[WIN], sum = 0.0;
    for (int i = 0; i < WIN; ++i) {
        double ax = (double)i - 5.0;
        gs[i] = exp(-(ax * ax) / 4.5);
        sum += gs[i];
    }
    for (int i = 0; i < WIN; ++i) gw.g[i] = (float)(gs[i] / sum);

    // workspace: 64B header (5 double acc), then pyramid
    double* acc = (double*)d_ws;
    float* base = (float*)((char*)d_ws + 64);
    const size_t n1 = 48ull * 256 * 256;
    const size_t n2 = 48ull * 128 * 128;
    const size_t n3 = 48ull * 64 * 64;
    const size_t n4 = 48ull * 32 * 32;
    float* a1 = base;      float* b1 = a1 + n1;
    float* a2 = b1 + n1;   float* b2 = a2 + n2;
    float* a3 = b2 + n2;   float* b3 = a3 + n3;
    float* a4 = b3 + n3;   float* b4 = a4 + n4;

    hipMemsetAsync(acc, 0, 5 * sizeof(double), stream);

    hipLaunchKernelGGL(ssim_l0_kernel, dim3(1536), dim3(256), 0, stream,
                       img1, img2, a1, b1, acc, gw);

    hipLaunchKernelGGL(pool_rest_kernel, dim3(16, 96), dim3(256), 0, stream,
                       a1, b1, a2, b2, a3, b3, a4, b4);

    hipLaunchKernelGGL(ssim_rest_kernel, dim3(516), dim3(256), 0, stream,
                       a1, b1, a2, b2, a3, b3, a4, b4, acc, gw);

    hipLaunchKernelGGL(final_kernel, dim3(1), dim3(1), 0, stream, acc, out);
}

// Round 5
// 263.090 us; speedup vs baseline: 1.7090x; 1.0561x over previous
//
#include <hip/hip_runtime.h>
#include <math.h>

#define WIN 11
#define PAD 5
#define TW 64              // tile width = wave width

typedef float v2f __attribute__((ext_vector_type(2)));

struct GW { float g[WIN]; };

// ---------------------------------------------------------------------------
// Wave-autonomous SSIM tile, STATIC-RING + BRANCHLESS-LOAD edition.
// R0..R4 established a hard invariant: per-wave row service ~1114 cyc,
// insensitive to instruction count (175-260), LDS bytes (1-2x), prefetch
// depth (1-2), resident waves (3-6/SIMD). VALU fills only ~430 cyc of it.
// Diagnosis: global loads sat inside divergent branches (if(cval)/if(hval)/
// y-guard) -> waitcnt insertion cannot statically count outstanding loads
// across branchy paths -> conservative vmcnt drain at every consume point ->
// full HBM latency exposed EVERY ROW; the depth-2 "prefetch" never engaged.
// Fix: BRANCHLESS loads. Clamp y/x into bounds, load unconditionally on all
// 64 lanes, zero results via selects. Halo lanes >=10 clamp to their own
// column (same cache line as main load -> no extra HBM). Uniform load count
// per row -> compiler emits counted vmcnt(N) -> pipeline finally covers
// latency with 2 row-bodies of work.
// Everything else identical to R4: LDS float2 (p,q); packed H-conv; V-conv
// static ring (u-unroll 11, compile-time slot roles, zero shift-movs);
// sched_barrier(0) pins row boundaries (R8 unroll-hoist spill trap);
// accumulators scalar float[11], static indices only (R1 spill trap).
// EMIT: L0 waves also pool rows pairwise into L1 (a=(P+Q)/2, b=(P-Q)/2).
// ---------------------------------------------------------------------------
template<bool EMIT>
__device__ __forceinline__ float ssim_wave_tile(
    const float* __restrict__ p1, const float* __restrict__ p2,
    int W, int X0, int Y0, const GW& gw, float2* __restrict__ rb,
    float* __restrict__ o1a, float* __restrict__ o1b, int Wout)
{
    const int TH = 32;
    const int lane = threadIdx.x & 63;
    const int gx = X0 + lane;
    const bool cval = gx < W;                              // false only for L4 lanes 32+
    const int hx   = (lane < 5) ? (X0 - 5 + lane) : (X0 + 59 + lane);
    const bool hval = (lane < 10) && ((unsigned)hx < (unsigned)W);
    const int hpos = (lane < 5) ? lane : (64 + lane);      // 0..4 | 69..73
    const int cpos = 5 + lane;
    const int gxc = cval ? gx : 0;                         // clamped main col
    const int hxc = hval ? hx : gxc;                       // masked halo -> own col (L1 hit)
    const int wpos = (lane < 10) ? hpos : cpos;            // branchless LDS halo write

    float vMp[11], vSp[11], vMq[11], vSq[11];
#pragma unroll
    for (int k = 0; k < 11; ++k) { vMp[k] = 0.f; vSp[k] = 0.f; vMq[k] = 0.f; vSq[k] = 0.f; }

    float part = 0.f;
    float pprev = 0.f, qprev = 0.f;

    // BRANCHLESS load: 4 unconditional global_load_dword per row, results
    // zero-selected. No exec-mask branches -> statically uniform vmcnt.
    auto LOAD = [&](int t, float& oa, float& ob, float& oah, float& obh) {
        int y = Y0 - PAD + t;
        bool yin = (unsigned)y < (unsigned)W;
        const float* r1 = p1 + (size_t)(yin ? y : 0) * W;
        const float* r2 = p2 + (size_t)(yin ? y : 0) * W;
        float va = r1[gxc], vb = r2[gxc];
        float wa = r1[hxc], wb = r2[hxc];
        bool cv = yin && cval;
        bool hv = yin && hval;
        oa  = cv ? va : 0.f;
        ob  = cv ? vb : 0.f;
        oah = hv ? wa : 0.f;
        obh = hv ? wb : 0.f;
    };

    // depth-2 prefetch pipeline: row t in (a0..), t+1 in (a1..)
    float a0, b0, ah0, bh0;
    float a1, b1, ah1, bh1;
    LOAD(0, a0, b0, ah0, bh0);
    LOAD(1, a1, b1, ah1, bh1);

#pragma unroll 1
    for (int blk = 0; blk < 4; ++blk) {
#pragma unroll
        for (int u = 0; u < 11; ++u) {
            const int t = blk * 11 + u;        // u compile-time, blk runtime

            // issue row t+2 now; consumed two full row-bodies from now
            float a2, b2, ah2, bh2;
            LOAD(t + 2, a2, b2, ah2, bh2);

            float p = a0 + b0, q = a0 - b0;
            float ph = ah0 + bh0, qh = ah0 - bh0;
            rb[cpos] = make_float2(p, q);
            // lanes<10: halo slot; lanes>=10: harmless same-value rewrite of own slot
            rb[wpos] = (lane < 10) ? make_float2(ph, qh) : make_float2(p, q);
            __builtin_amdgcn_wave_barrier();   // writes -> reads (cross-lane RAW)

            v2f hM = {0.f, 0.f}, hS = {0.f, 0.f};
#pragma unroll
            for (int j = 0; j < WIN; ++j) {
                float2 v = rb[lane + j];
                v2f vm = { v.x, v.y };
                v2f g2 = { gw.g[j], gw.g[j] };
                hM = __builtin_elementwise_fma(g2, vm, hM);
                hS = __builtin_elementwise_fma(g2, vm * vm, hS);
            }
            __builtin_amdgcn_wave_barrier();   // reads -> next row's writes (WAR)
            float hp = hM.x, hq = hM.y, hpp = hS.x, hqq = hS.y;

            // V-conv static ring: slot s, row t: weight g[10 - ((s-t) mod 11)]
#pragma unroll
            for (int s = 0; s < 11; ++s) {
                const int widx = 10 - ((s - u + 11) % 11);
                float g = gw.g[widx];
                vMp[s] = fmaf(g, hp,  vMp[s]);
                vSp[s] = fmaf(g, hpp, vSp[s]);
                vMq[s] = fmaf(g, hq,  vMq[s]);
                vSq[s] = fmaf(g, hqq, vSq[s]);
            }

            if (EMIT) {
                if (t >= 6 && t <= TH + 4 && (t & 1) == 0) {   // pool rows (t-1, t)
                    float sp_ = p + pprev, sq_ = q + qprev;
                    float sp2 = sp_ + __shfl_down(sp_, 1, 64);
                    float sq2 = sq_ + __shfl_down(sq_, 1, 64);
                    if ((lane & 1) == 0) {
                        float P = sp2 * 0.25f, Q = sq2 * 0.25f;
                        int yo = (t - 6) >> 1;
                        size_t oo = (size_t)((Y0 >> 1) + yo) * Wout + ((X0 >> 1) + (lane >> 1));
                        o1a[oo] = (P + Q) * 0.5f;
                        o1b[oo] = (P - Q) * 0.5f;
                    }
                }
                pprev = p; qprev = q;
            }

            // slot u completes output o = t-10 this row (after its g[10] tap)
            {
                int o = t - 10;
                if ((unsigned)o < (unsigned)TH) {
                    bool yok = (unsigned)(Y0 + o) < (unsigned)W;   // false only for L4 tail
                    float Mp = vMp[u], Sp_ = vSp[u], Mq = vMq[u], Sq_ = vSq[u];
                    const float C1v = 1e-4f, C2v = 9e-4f;
                    float A = Mp * Mp, B = Mq * Mq;
                    float ABp = A + B, ABm = A - B;
                    float SSp = Sp_ + Sq_, SSm = Sp_ - Sq_;
                    float n1 = fmaf(0.5f, ABm, C1v);         // 2*m12 + C1
                    float n2 = fmaf(0.5f, SSm - ABm, C2v);   // 2*s12 + C2
                    float e1 = fmaf(0.5f, ABp, C1v);         // m1^2+m2^2 + C1
                    float e2 = fmaf(0.5f, SSp - ABp, C2v);   // s1+s2 + C2
                    float v = (n1 * n2) * __builtin_amdgcn_rcpf(e1 * e2);
                    part += (cval && yok) ? v : 0.f;
                }
                vMp[u] = 0.f; vSp[u] = 0.f; vMq[u] = 0.f; vSq[u] = 0.f;
            }

            // rotate prefetch pipeline
            a0 = a1; b0 = b1; ah0 = ah1; bh0 = bh1;
            a1 = a2; b1 = b2; ah1 = ah2; bh1 = bh2;

            // pin row boundary: no load hoisting / cross-row motion (R8 trap)
            __builtin_amdgcn_sched_barrier(0);
        }
    }

    return part;
}

// ---- L0: 8x16 tiles (64x32) x 48 images = 6144 waves (1536 blocks); emits L1 ----
__global__ __launch_bounds__(256, 4) void ssim_l0_kernel(
    const float* __restrict__ i1, const float* __restrict__ i2,
    float* __restrict__ a1, float* __restrict__ b1,
    double* __restrict__ acc, GW gw)
{
    __shared__ float2 rbs[4][80];
    const int wid = threadIdx.x >> 6;
    const int w = blockIdx.x * 4 + wid;
    const int img = w >> 7;                 // 128 tiles per image
    const int tt = w & 127;
    const int tx = tt & 7, ty = tt >> 3;    // 8 cols x 16 rows
    const size_t off  = (size_t)img * 512 * 512;
    const size_t ooff = (size_t)img * 256 * 256;

    float part = ssim_wave_tile<true>(i1 + off, i2 + off, 512, tx * 64, ty * 32,
                                      gw, rbs[wid], a1 + ooff, b1 + ooff, 256);
#pragma unroll
    for (int o = 32; o > 0; o >>= 1) part += __shfl_down(part, o, 64);
    if ((threadIdx.x & 63) == 0) atomicAdd(acc, (double)part);
}

// ---- L1..L4, all 64x32 tiles: 32+8+2+1 = 43 tiles/image = 2064 waves
//      (516 blocks). TH=32 cuts halo overhead to 1.31 rows/output. ----
__global__ __launch_bounds__(256, 4) void ssim_rest_kernel(
    const float* __restrict__ a1, const float* __restrict__ b1,
    const float* __restrict__ a2, const float* __restrict__ b2,
    const float* __restrict__ a3, const float* __restrict__ b3,
    const float* __restrict__ a4, const float* __restrict__ b4,
    double* __restrict__ acc, GW gw)
{
    __shared__ float2 rbs[4][80];
    const int wid = threadIdx.x >> 6;
    const int w = blockIdx.x * 4 + wid;
    const int img = w / 43;
    const int r = w - img * 43;
    int lvl, tx, ty;
    if (r < 32)      { lvl = 1; tx = r & 3;  ty = r >> 2; }                // 4x8
    else if (r < 40) { lvl = 2; int s = r - 32; tx = s & 1; ty = s >> 1; } // 2x4
    else if (r < 42) { lvl = 3; tx = 0; ty = r - 40; }                     // 1x2
    else             { lvl = 4; tx = 0; ty = 0; }                          // 1x1
    const int W = 512 >> lvl;
    const float* p1; const float* p2;
    switch (lvl) {
      case 1:  p1 = a1; p2 = b1; break;
      case 2:  p1 = a2; p2 = b2; break;
      case 3:  p1 = a3; p2 = b3; break;
      default: p1 = a4; p2 = b4; break;
    }
    const size_t off = (size_t)img * W * W;

    float part = ssim_wave_tile<false>(p1 + off, p2 + off, W, tx * 64, ty * 32,
                                       gw, rbs[wid], nullptr, nullptr, 0);
#pragma unroll
    for (int o = 32; o > 0; o >>= 1) part += __shfl_down(part, o, 64);
    if ((threadIdx.x & 63) == 0) atomicAdd(acc + lvl, (double)part);
}

// ---- pool L1 -> L2/L3/L4. Grid (16, 96). ----
__global__ __launch_bounds__(256) void pool_rest_kernel(
    const float* __restrict__ a1, const float* __restrict__ b1,
    float* __restrict__ a2, float* __restrict__ b2,
    float* __restrict__ a3, float* __restrict__ b3,
    float* __restrict__ a4, float* __restrict__ b4)
{
    __shared__ float l2[32][33];
    __shared__ float l3[16][17];
    const int tid = threadIdx.x;
    const int im = blockIdx.y;
    const int tb = blockIdx.x;
    const int tx = tb & 3, ty = tb >> 2;
    const bool second = im >= 48;
    const int ii = second ? im - 48 : im;
    const float* src = (second ? b1 : a1) + (size_t)ii * 256 * 256;
    float* o2 = (second ? b2 : a2) + (size_t)ii * 128 * 128;
    float* o3 = (second ? b3 : a3) + (size_t)ii * 64 * 64;
    float* o4 = (second ? b4 : a4) + (size_t)ii * 32 * 32;
    const int X0 = tx * 64, Y0 = ty * 64;

#pragma unroll
    for (int k = 0; k < 2; ++k) {
        int idx = tid + k * 256;
        int xp = idx & 15;
        int yo = idx >> 4;
        const float* rp = src + (size_t)(Y0 + 2 * yo) * 256 + (X0 + 4 * xp);
        float4 r0 = *(const float4*)rp;
        float4 r1 = *(const float4*)(rp + 256);
        float v0 = (r0.x + r0.y + r1.x + r1.y) * 0.25f;
        float v1 = (r0.z + r0.w + r1.z + r1.w) * 0.25f;
        l2[yo][2 * xp]     = v0;
        l2[yo][2 * xp + 1] = v1;
        float2* op = (float2*)(o2 + (size_t)((Y0 >> 1) + yo) * 128 + ((X0 >> 1) + 2 * xp));
        *op = make_float2(v0, v1);
    }
    __syncthreads();
    {
        int xo = tid & 15, yo = tid >> 4;
        if (yo < 16) {
            float v = (l2[2*yo][2*xo] + l2[2*yo][2*xo+1] +
                       l2[2*yo+1][2*xo] + l2[2*yo+1][2*xo+1]) * 0.25f;
            l3[yo][xo] = v;
            o3[(size_t)((Y0 >> 2) + yo) * 64 + ((X0 >> 2) + xo)] = v;
        }
    }
    __syncthreads();
    if (tid < 64) {
        int xo = tid & 7, yo = tid >> 3;
        float v = (l3[2*yo][2*xo] + l3[2*yo][2*xo+1] +
                   l3[2*yo+1][2*xo] + l3[2*yo+1][2*xo+1]) * 0.25f;
        o4[(size_t)((Y0 >> 3) + yo) * 32 + ((X0 >> 3) + xo)] = v;
    }
}

__global__ void final_kernel(const double* __restrict__ acc, float* __restrict__ out)
{
    double loss = 0.0;
#pragma unroll
    for (int l = 0; l < 5; ++l) {
        double cnt = 48.0 * (double)(512 >> l) * (double)(512 >> l);
        loss += 1.0 - acc[l] / cnt;
    }
    out[0] = (float)loss;
}

extern "C" void kernel_launch(void* const* d_in, const int* in_sizes, int n_in,
                              void* d_out, int out_size, void* d_ws, size_t ws_size,
                              hipStream_t stream)
{
    const float* img1 = (const float*)d_in[0];
    const float* img2 = (const float*)d_in[1];
    float* out = (float*)d_out;

    // 1D gaussian (sigma=1.5, k=11), matches reference construction
    GW gw;
    double gs[WIN], sum = 0.0;
    for (int i = 0; i < WIN; ++i) {
        double ax = (double)i - 5.0;
        gs[i] = exp(-(ax * ax) / 4.5);
        sum += gs[i];
    }
    for (int i = 0; i < WIN; ++i) gw.g[i] = (float)(gs[i] / sum);

    // workspace: 64B header (5 double acc), then pyramid
    double* acc = (double*)d_ws;
    float* base = (float*)((char*)d_ws + 64);
    const size_t n1 = 48ull * 256 * 256;
    const size_t n2 = 48ull * 128 * 128;
    const size_t n3 = 48ull * 64 * 64;
    const size_t n4 = 48ull * 32 * 32;
    float* a1 = base;      float* b1 = a1 + n1;
    float* a2 = b1 + n1;   float* b2 = a2 + n2;
    float* a3 = b2 + n2;   float* b3 = a3 + n3;
    float* a4 = b3 + n3;   float* b4 = a4 + n4;

    hipMemsetAsync(acc, 0, 5 * sizeof(double), stream);

    hipLaunchKernelGGL(ssim_l0_kernel, dim3(1536), dim3(256), 0, stream,
                       img1, img2, a1, b1, acc, gw);

    hipLaunchKernelGGL(pool_rest_kernel, dim3(16, 96), dim3(256), 0, stream,
                       a1, b1, a2, b2, a3, b3, a4, b4);

    hipLaunchKernelGGL(ssim_rest_kernel, dim3(516), dim3(256), 0, stream,
                       a1, b1, a2, b2, a3, b3, a4, b4, acc, gw);

    hipLaunchKernelGGL(final_kernel, dim3(1), dim3(1), 0, stream, acc, out);
}